// Round 4
// baseline (727.039 us; speedup 1.0000x reference)
//
#include <hip/hip_runtime.h>
#include <math.h>

// B=4, S=1024, E=1024, H=16, Dh=64
#define SS 1024
#define OUT0_SZ (4*1024*1024)

typedef _Float16 f16;
typedef _Float16 h8 __attribute__((ext_vector_type(8)));
typedef _Float16 h4 __attribute__((ext_vector_type(4)));
typedef float f32x4 __attribute__((ext_vector_type(4)));

#define MFMA(a,b,c) __builtin_amdgcn_mfma_f32_16x16x32_f16(a, b, c, 0, 0, 0)

__device__ __forceinline__ void gload_lds16(const void* g, void* l) {
  __builtin_amdgcn_global_load_lds((const __attribute__((address_space(1))) void*)g,
                                   (__attribute__((address_space(3))) void*)l, 16, 0, 0);
}

// ---------------------------------------------------------------------------
// transpose + (optional split) fp32 [K][N] -> f16 [N][K], scaled by `scale`
// ---------------------------------------------------------------------------
template<int SPLIT>
__global__ __launch_bounds__(256)
void transpose_split(const float* __restrict__ in, f16* __restrict__ outHi,
                     f16* __restrict__ outLo, int K, int N, float scale) {
  __shared__ float t[32][33];
  const int n0 = blockIdx.x * 32, k0 = blockIdx.y * 32;
  const int tx = threadIdx.x & 31, ty = threadIdx.x >> 5;   // ty 0..7
#pragma unroll
  for (int j = 0; j < 4; j++)
    t[ty + j * 8][tx] = in[(size_t)(k0 + ty + j * 8) * N + n0 + tx] * scale;
  __syncthreads();
#pragma unroll
  for (int j = 0; j < 4; j++) {
    float v = t[tx][ty + j * 8];
    f16 h = (f16)v;
    size_t idx = (size_t)(n0 + ty + j * 8) * K + k0 + tx;
    outHi[idx] = h;
    if (SPLIT) outLo[idx] = (f16)(v - (float)h);
  }
}

// ---------------------------------------------------------------------------
// elementwise split: x fp32 -> (x*64) hi/lo f16   (bitwise same as in-kernel)
// ---------------------------------------------------------------------------
__global__ __launch_bounds__(256)
void splitx(const float* __restrict__ x, f16* __restrict__ hi, f16* __restrict__ lo) {
  const size_t i4 = (size_t)blockIdx.x * 256 + threadIdx.x;   // float4 index
  float4 v = ((const float4*)x)[i4];
  float vv[4] = {v.x, v.y, v.z, v.w};
  h4 hh, ll;
#pragma unroll
  for (int j = 0; j < 4; j++) {
    float sv = vv[j] * 64.f;
    f16 h = (f16)sv;
    hh[j] = h; ll[j] = (f16)(sv - (float)h);
  }
  ((h4*)hi)[i4] = hh;
  ((h4*)lo)[i4] = ll;
}

// ---------------------------------------------------------------------------
// V transpose: f16 [bh][1024 s][64 d] -> [bh][64 d][1024 s]
// ---------------------------------------------------------------------------
__global__ __launch_bounds__(256)
void transpose_v(const f16* __restrict__ in, f16* __restrict__ out) {
  __shared__ f16 t[32][33];
  const int bh = blockIdx.z, s0 = blockIdx.x * 32, d0 = blockIdx.y * 32;
  in  += (size_t)bh * 65536;
  out += (size_t)bh * 65536;
  const int tx = threadIdx.x & 31, ty = threadIdx.x >> 5;
#pragma unroll
  for (int j = 0; j < 4; j++)
    t[ty + j * 8][tx] = in[(size_t)(s0 + ty + j * 8) * 64 + d0 + tx];
  __syncthreads();
#pragma unroll
  for (int j = 0; j < 4; j++)
    out[(size_t)(d0 + ty + j * 8) * 1024 + s0 + tx] = t[tx][ty + j * 8];
}

// ---------------------------------------------------------------------------
// QKV GEMM: split-f16 MFMA.  Xhi/Xlo f16 [4096][1024] (A, global_load_lds);
// WhiT/WloT f16 [3072 n][1024 k] (B, global_load_lds, pre-scaled 2^12).
// acc * 2^-18 + bias -> scatter: q,k re-split (scale 2^6); v -> f16 Vf.
// ---------------------------------------------------------------------------
__global__ __launch_bounds__(256)
void qkv_gemm(const f16* __restrict__ Xhi, const f16* __restrict__ Xlo,
              const f16* __restrict__ WhiT, const f16* __restrict__ WloT,
              const float* __restrict__ bias,
              f16* __restrict__ Qhi, f16* __restrict__ Qlo,
              f16* __restrict__ Khi, f16* __restrict__ Klo, f16* __restrict__ Vf) {
  __shared__ __align__(16) f16 Ah[128 * 32], Al[128 * 32], Bh[128 * 32], Bl[128 * 32];
  const int tid = threadIdx.x, w = tid >> 6, l = tid & 63;
  const int n0 = blockIdx.x * 128, m0 = blockIdx.y * 128;
  const int wr = (w & 1) * 64, wc = (w >> 1) * 64;
  const int fr = l & 15, fq = l >> 4;
  f32x4 acc[4][4] = {};

  for (int kt = 0; kt < 1024; kt += 32) {
    __syncthreads();
#pragma unroll
    for (int i = 0; i < 2; i++) {
      int row = w * 32 + i * 16 + (l >> 2);
      int co = kt + (l & 3) * 8;
      size_t aoff = (size_t)(m0 + row) * 1024 + co;
      size_t boff = (size_t)(n0 + row) * 1024 + co;
      gload_lds16(Xhi  + aoff, Ah + w * 1024 + i * 512);
      gload_lds16(Xlo  + aoff, Al + w * 1024 + i * 512);
      gload_lds16(WhiT + boff, Bh + w * 1024 + i * 512);
      gload_lds16(WloT + boff, Bl + w * 1024 + i * 512);
    }
    __syncthreads();
    h8 ah[4], al[4], bh[4], bl[4];
#pragma unroll
    for (int m = 0; m < 4; m++) {
      ah[m] = *(h8*)&Ah[(wr + m * 16 + fr) * 32 + fq * 8];
      al[m] = *(h8*)&Al[(wr + m * 16 + fr) * 32 + fq * 8];
    }
#pragma unroll
    for (int n = 0; n < 4; n++) {
      bh[n] = *(h8*)&Bh[(wc + n * 16 + fr) * 32 + fq * 8];
      bl[n] = *(h8*)&Bl[(wc + n * 16 + fr) * 32 + fq * 8];
    }
#pragma unroll
    for (int m = 0; m < 4; m++)
#pragma unroll
      for (int n = 0; n < 4; n++) {
        acc[m][n] = MFMA(ah[m], bh[n], acc[m][n]);
        acc[m][n] = MFMA(al[m], bh[n], acc[m][n]);
        acc[m][n] = MFMA(ah[m], bl[n], acc[m][n]);
      }
  }

#pragma unroll
  for (int m = 0; m < 4; m++)
#pragma unroll
    for (int n = 0; n < 4; n++)
#pragma unroll
      for (int j = 0; j < 4; j++) {
        int row = m0 + wr + m * 16 + fq * 4 + j;
        int col = n0 + wc + n * 16 + fr;
        float val = acc[m][n][j] * (1.f / 262144.f) + bias[col];
        int t = col >> 10, h = (col >> 6) & 15, d = col & 63;
        int b = row >> 10, s = row & 1023;
        size_t idx = ((size_t)(b * 16 + h) * 1024 + s) * 64 + d;
        if (t == 0) { f16 hh = (f16)(val * 64.f); Qhi[idx] = hh; Qlo[idx] = (f16)(val * 64.f - (float)hh); }
        else if (t == 1) { f16 hh = (f16)(val * 64.f); Khi[idx] = hh; Klo[idx] = (f16)(val * 64.f - (float)hh); }
        else Vf[idx] = (f16)val;
      }
}

// ---------------------------------------------------------------------------
// FUSED QK^T + softmax/threshold/argmax-filter.  Per block: 32 rows x 1024
// cols of fp32 logits in padded LDS; K hi/lo streamed in 64-row chunks with
// XOR-swizzled staging (kills the 128B-row 16-way bank conflict); Q frags in
// registers.  Writes filtered_attn fp32 directly (att never round-trips).
// MFMA product order identical to round-3 qk_gemm -> bitwise-same logits.
// ---------------------------------------------------------------------------
__global__ __launch_bounds__(256)
void qksm(const f16* __restrict__ Qhi, const f16* __restrict__ Qlo,
          const f16* __restrict__ Khi, const f16* __restrict__ Klo,
          float* __restrict__ att) {
  __shared__ float P[32][1028];                      // 131584 B, rows 16B-aligned, bank stride 4
  __shared__ __align__(16) f16 KH[4096], KL[4096];   // 8 KB each: 64 rows x 64 k
  const int bh = blockIdx.y, m0 = blockIdx.x * 32;
  const size_t off = (size_t)bh * 65536;
  const int tid = threadIdx.x, w = tid >> 6, l = tid & 63;
  const int fr = l & 15, fq = l >> 4;
  const int nw = w * 16;

  // Q fragments (rows m0..m0+31), register-resident for the whole block
  h8 qh[2][2], ql[2][2];
#pragma unroll
  for (int m = 0; m < 2; m++)
#pragma unroll
    for (int kk = 0; kk < 2; kk++) {
      size_t o = off + (size_t)(m0 + 16 * m + fr) * 64 + kk * 32 + fq * 8;
      qh[m][kk] = *(const h8*)(Qhi + o);
      ql[m][kk] = *(const h8*)(Qlo + o);
    }

  const char* KhiB = (const char*)(Khi + off);
  const char* KloB = (const char*)(Klo + off);

  for (int c = 0; c < 16; c++) {
    // stage chunk rows c*64..c*64+63 (S-cols), source pre-swizzled so that
    // LDS[r][b] = G[r][b ^ ((r&7)<<4)]  (16B-granular involution)
    {
      int i0 = w * 2;
#pragma unroll
      for (int i = i0; i < i0 + 2; i++) {
        int r = i * 8 + (l >> 3);
        size_t gb = (size_t)(c * 64 + r) * 128 + (size_t)(((l & 7) * 16) ^ ((r & 7) << 4));
        gload_lds16(KhiB + gb, (char*)KH + i * 1024);
        gload_lds16(KloB + gb, (char*)KL + i * 1024);
      }
    }
    __syncthreads();
    f32x4 acc[2] = {};
    const int R = nw + fr;
    const int rs = (R & 7) << 4;
#pragma unroll
    for (int kk = 0; kk < 2; kk++) {
      h8 b_h = *(const h8*)((const char*)KH + R * 128 + ((kk * 64 + fq * 16) ^ rs));
      h8 b_l = *(const h8*)((const char*)KL + R * 128 + ((kk * 64 + fq * 16) ^ rs));
#pragma unroll
      for (int m = 0; m < 2; m++) {
        acc[m] = MFMA(qh[m][kk], b_h, acc[m]);
        acc[m] = MFMA(ql[m][kk], b_h, acc[m]);
        acc[m] = MFMA(qh[m][kk], b_l, acc[m]);
      }
    }
    // logits -> LDS (C layout: col=lane&15, row=(lane>>4)*4+j)
#pragma unroll
    for (int m = 0; m < 2; m++)
#pragma unroll
      for (int j = 0; j < 4; j++)
        P[16 * m + fq * 4 + j][c * 64 + nw + fr] = acc[m][j] * (1.f / 32768.f);
    __syncthreads();
  }

  // per-row wave-parallel softmax -> filter -> direct global store
  const int r0 = w * 8;
  for (int rr = 0; rr < 8; rr++) {
    const int r = r0 + rr;
    float z[16];
#pragma unroll
    for (int i = 0; i < 16; i++) z[i] = P[r][l + 64 * i];
    float m = z[0]; int am = l;
#pragma unroll
    for (int i = 1; i < 16; i++) { int idx = l + 64 * i; if (z[i] > m) { m = z[i]; am = idx; } }
#pragma unroll
    for (int o = 32; o >= 1; o >>= 1) {
      float om = __shfl_xor(m, o, 64);
      int oa = __shfl_xor(am, o, 64);
      if (om > m || (om == m && oa < am)) { m = om; am = oa; }
    }
    float e[16]; float s = 0.f;
#pragma unroll
    for (int i = 0; i < 16; i++) { e[i] = expf(z[i] - m); s += e[i]; }
#pragma unroll
    for (int o = 32; o >= 1; o >>= 1) s += __shfl_xor(s, o, 64);
    bool sel[16]; float fl = 0.f; int anyl = 0;
#pragma unroll
    for (int i = 0; i < 16; i++) {
      sel[i] = (e[i] / s > 0.1f);
      if (sel[i]) { fl += e[i]; anyl = 1; }
    }
#pragma unroll
    for (int o = 32; o >= 1; o >>= 1) fl += __shfl_xor(fl, o, 64);
    int any = __any(anyl);
    float* arow = att + ((size_t)bh << 20) + (size_t)(m0 + r) * 1024;
#pragma unroll
    for (int i = 0; i < 16; i++) {
      float v;
      if (any) v = sel[i] ? e[i] / fl : 0.f;
      else     v = ((l + 64 * i) == am) ? 1.f : 0.f;
      arow[l + 64 * i] = v;
    }
  }
}

// ---------------------------------------------------------------------------
// PV: batched f16 MFMA.  A = filtered_attn fp32 (reg-staged->f16; one-hots
// are exact), B = Vt f16 [bh][64 d][1024 s].  Tile 128x64. Out: ao16 f16.
// ---------------------------------------------------------------------------
__global__ __launch_bounds__(256)
void pv_gemm(const float* __restrict__ att, const f16* __restrict__ Vt,
             f16* __restrict__ ao) {
  __shared__ __align__(16) f16 A[128 * 32], B[64 * 32];
  const int bh = blockIdx.y, m0 = blockIdx.x * 128;
  const float* fa = att + (size_t)bh * 1048576;
  const f16* Vb = Vt + (size_t)bh * 65536;
  const int tid = threadIdx.x, w = tid >> 6, l = tid & 63;
  const int wr = (w & 1) * 64, wc = (w >> 1) * 32;
  const int fr = l & 15, fq = l >> 4;
  f32x4 acc[4][2] = {};

  for (int kt = 0; kt < 1024; kt += 32) {
    __syncthreads();
    {
      int row = w * 16 + (l >> 2);
      gload_lds16(Vb + (size_t)row * 1024 + kt + (l & 3) * 8, B + w * 512);
    }
#pragma unroll
    for (int r4 = 0; r4 < 4; r4++) {
      int f = r4 * 256 + tid;
      int row = f >> 3, c4 = (f & 7) * 4;
      float4 pv4 = *(const float4*)&fa[(size_t)(m0 + row) * 1024 + kt + c4];
      h4 hh;
      hh[0] = (f16)pv4.x; hh[1] = (f16)pv4.y; hh[2] = (f16)pv4.z; hh[3] = (f16)pv4.w;
      *(h4*)&A[row * 32 + c4] = hh;
    }
    __syncthreads();
    h8 a[4], b[2];
#pragma unroll
    for (int m = 0; m < 4; m++) a[m] = *(h8*)&A[(wr + m * 16 + fr) * 32 + fq * 8];
#pragma unroll
    for (int n = 0; n < 2; n++) b[n] = *(h8*)&B[(wc + n * 16 + fr) * 32 + fq * 8];
#pragma unroll
    for (int m = 0; m < 4; m++)
#pragma unroll
      for (int n = 0; n < 2; n++) acc[m][n] = MFMA(a[m], b[n], acc[m][n]);
  }

  const int b = bh >> 4, h = bh & 15;
#pragma unroll
  for (int m = 0; m < 4; m++)
#pragma unroll
    for (int n = 0; n < 2; n++)
#pragma unroll
      for (int j = 0; j < 4; j++) {
        int s = m0 + wr + m * 16 + fq * 4 + j;
        int d = wc + n * 16 + fr;
        ao[((size_t)(b * 1024 + s)) * 1024 + h * 64 + d] = (f16)acc[m][n][j];
      }
}

// ---------------------------------------------------------------------------
// proj: plain f16 MFMA.  A = ao16 [4096][1024], B = WpT [1024 n][1024 k].
// out fp32 = acc + bias.
// ---------------------------------------------------------------------------
__global__ __launch_bounds__(256)
void proj_gemm(const f16* __restrict__ ao, const f16* __restrict__ WpT,
               const float* __restrict__ bias, float* __restrict__ out) {
  __shared__ __align__(16) f16 A[128 * 32], B[128 * 32];
  const int tid = threadIdx.x, w = tid >> 6, l = tid & 63;
  const int n0 = blockIdx.x * 128, m0 = blockIdx.y * 128;
  const int wr = (w & 1) * 64, wc = (w >> 1) * 64;
  const int fr = l & 15, fq = l >> 4;
  f32x4 acc[4][4] = {};

  for (int kt = 0; kt < 1024; kt += 32) {
    __syncthreads();
#pragma unroll
    for (int i = 0; i < 2; i++) {
      int row = w * 32 + i * 16 + (l >> 2);
      gload_lds16(ao  + (size_t)(m0 + row) * 1024 + kt + (l & 3) * 8, A + w * 1024 + i * 512);
      gload_lds16(WpT + (size_t)(n0 + row) * 1024 + kt + (l & 3) * 8, B + w * 1024 + i * 512);
    }
    __syncthreads();
    h8 a[4], b[4];
#pragma unroll
    for (int m = 0; m < 4; m++) a[m] = *(h8*)&A[(wr + m * 16 + fr) * 32 + fq * 8];
#pragma unroll
    for (int n = 0; n < 4; n++) b[n] = *(h8*)&B[(wc + n * 16 + fr) * 32 + fq * 8];
#pragma unroll
    for (int m = 0; m < 4; m++)
#pragma unroll
      for (int n = 0; n < 4; n++) acc[m][n] = MFMA(a[m], b[n], acc[m][n]);
  }

#pragma unroll
  for (int m = 0; m < 4; m++)
#pragma unroll
    for (int n = 0; n < 4; n++)
#pragma unroll
      for (int j = 0; j < 4; j++) {
        int row = m0 + wr + m * 16 + fq * 4 + j;
        int col = n0 + wc + n * 16 + fr;
        out[(size_t)row * 1024 + col] = acc[m][n][j] + bias[col];
      }
}

// ---------------------------------------------------------------------------
extern "C" void kernel_launch(void* const* d_in, const int* in_sizes, int n_in,
                              void* d_out, int out_size, void* d_ws, size_t ws_size,
                              hipStream_t stream) {
  const float* x      = (const float*)d_in[0];
  const float* w_qkv  = (const float*)d_in[1];
  const float* b_qkv  = (const float*)d_in[2];
  const float* w_proj = (const float*)d_in[3];
  const float* b_proj = (const float*)d_in[4];

  float* out0 = (float*)d_out;
  float* att  = out0 + OUT0_SZ;            // [B,H,S,S] filtered_attn (output)

  // x hi/lo split parked in the att region (dead until qksm writes it)
  f16* Xhi = (f16*)att;                    // 8 MB
  f16* Xlo = Xhi + 4194304;                // 8 MB  (16 MB << 268 MB region)

  f16* ws16 = (f16*)d_ws;                  // 65.0 MB peak (proven available)
  f16* WhiT = ws16;                        // [3072][1024]
  f16* WloT = ws16 +  3145728;
  f16* WpT  = ws16 +  6291456;             // [1024][1024]
  f16* Qhi  = ws16 +  7340032;             // [64][1024][64] each
  f16* Qlo  = ws16 + 11534336;
  f16* Khi  = ws16 + 15728640;
  f16* Klo  = ws16 + 19922944;
  f16* Vf   = ws16 + 24117248;             // [64][1024][64]
  f16* Vt   = ws16 + 28311552;             // [64][64][1024]
  f16* ao16 = ws16;                        // aliases WhiT/WloT (dead after qkv)

  transpose_split<1><<<dim3(96, 32), 256, 0, stream>>>(w_qkv, WhiT, WloT, 1024, 3072, 4096.f);
  transpose_split<0><<<dim3(32, 32), 256, 0, stream>>>(w_proj, WpT, nullptr, 1024, 1024, 1.f);
  splitx<<<4096, 256, 0, stream>>>(x, Xhi, Xlo);
  qkv_gemm<<<dim3(24, 32), 256, 0, stream>>>(Xhi, Xlo, WhiT, WloT, b_qkv, Qhi, Qlo, Khi, Klo, Vf);
  transpose_v<<<dim3(32, 2, 64), 256, 0, stream>>>(Vf, Vt);
  qksm<<<dim3(32, 64), 256, 0, stream>>>(Qhi, Qlo, Khi, Klo, att);
  pv_gemm<<<dim3(8, 64), 256, 0, stream>>>(att, Vt, ao16);
  proj_gemm<<<dim3(8, 32), 256, 0, stream>>>(ao16, WpT, b_proj, out0);
}

// Round 5
// 651.158 us; speedup vs baseline: 1.1165x; 1.1165x over previous
//
#include <hip/hip_runtime.h>
#include <math.h>

// B=4, S=1024, E=1024, H=16, Dh=64
#define SS 1024
#define OUT0_SZ (4*1024*1024)

typedef _Float16 f16;
typedef _Float16 h8 __attribute__((ext_vector_type(8)));
typedef _Float16 h4 __attribute__((ext_vector_type(4)));
typedef float f32x4 __attribute__((ext_vector_type(4)));

#define MFMA(a,b,c) __builtin_amdgcn_mfma_f32_16x16x32_f16(a, b, c, 0, 0, 0)

__device__ __forceinline__ void gload_lds16(const void* g, void* l) {
  __builtin_amdgcn_global_load_lds((const __attribute__((address_space(1))) void*)g,
                                   (__attribute__((address_space(3))) void*)l, 16, 0, 0);
}

// ---------------------------------------------------------------------------
// transpose + (optional split) fp32 [K][N] -> f16 [N][K], scaled by `scale`
// ---------------------------------------------------------------------------
template<int SPLIT>
__global__ __launch_bounds__(256)
void transpose_split(const float* __restrict__ in, f16* __restrict__ outHi,
                     f16* __restrict__ outLo, int K, int N, float scale) {
  __shared__ float t[32][33];
  const int n0 = blockIdx.x * 32, k0 = blockIdx.y * 32;
  const int tx = threadIdx.x & 31, ty = threadIdx.x >> 5;   // ty 0..7
#pragma unroll
  for (int j = 0; j < 4; j++)
    t[ty + j * 8][tx] = in[(size_t)(k0 + ty + j * 8) * N + n0 + tx] * scale;
  __syncthreads();
#pragma unroll
  for (int j = 0; j < 4; j++) {
    float v = t[tx][ty + j * 8];
    f16 h = (f16)v;
    size_t idx = (size_t)(n0 + ty + j * 8) * K + k0 + tx;
    outHi[idx] = h;
    if (SPLIT) outLo[idx] = (f16)(v - (float)h);
  }
}

// ---------------------------------------------------------------------------
// elementwise split: x fp32 -> (x*64) hi/lo f16
// ---------------------------------------------------------------------------
__global__ __launch_bounds__(256)
void splitx(const float* __restrict__ x, f16* __restrict__ hi, f16* __restrict__ lo) {
  const size_t i4 = (size_t)blockIdx.x * 256 + threadIdx.x;   // float4 index
  float4 v = ((const float4*)x)[i4];
  float vv[4] = {v.x, v.y, v.z, v.w};
  h4 hh, ll;
#pragma unroll
  for (int j = 0; j < 4; j++) {
    float sv = vv[j] * 64.f;
    f16 h = (f16)sv;
    hh[j] = h; ll[j] = (f16)(sv - (float)h);
  }
  ((h4*)hi)[i4] = hh;
  ((h4*)lo)[i4] = ll;
}

// ---------------------------------------------------------------------------
// V transpose: f16 [bh][1024 s][64 d] -> [bh][64 d][1024 s]
// ---------------------------------------------------------------------------
__global__ __launch_bounds__(256)
void transpose_v(const f16* __restrict__ in, f16* __restrict__ out) {
  __shared__ f16 t[32][33];
  const int bh = blockIdx.z, s0 = blockIdx.x * 32, d0 = blockIdx.y * 32;
  in  += (size_t)bh * 65536;
  out += (size_t)bh * 65536;
  const int tx = threadIdx.x & 31, ty = threadIdx.x >> 5;
#pragma unroll
  for (int j = 0; j < 4; j++)
    t[ty + j * 8][tx] = in[(size_t)(s0 + ty + j * 8) * 64 + d0 + tx];
  __syncthreads();
#pragma unroll
  for (int j = 0; j < 4; j++)
    out[(size_t)(d0 + ty + j * 8) * 1024 + s0 + tx] = t[tx][ty + j * 8];
}

// ---------------------------------------------------------------------------
// QKV GEMM: split-f16 MFMA.  Xhi/Xlo f16 [4096][1024] (A, global_load_lds);
// WhiT/WloT f16 [3072 n][1024 k] (B, global_load_lds, pre-scaled 2^12).
// acc * 2^-18 + bias -> scatter: q,k re-split (scale 2^6); v -> f16 Vf.
// ---------------------------------------------------------------------------
__global__ __launch_bounds__(256)
void qkv_gemm(const f16* __restrict__ Xhi, const f16* __restrict__ Xlo,
              const f16* __restrict__ WhiT, const f16* __restrict__ WloT,
              const float* __restrict__ bias,
              f16* __restrict__ Qhi, f16* __restrict__ Qlo,
              f16* __restrict__ Khi, f16* __restrict__ Klo, f16* __restrict__ Vf) {
  __shared__ __align__(16) f16 Ah[128 * 32], Al[128 * 32], Bh[128 * 32], Bl[128 * 32];
  const int tid = threadIdx.x, w = tid >> 6, l = tid & 63;
  const int n0 = blockIdx.x * 128, m0 = blockIdx.y * 128;
  const int wr = (w & 1) * 64, wc = (w >> 1) * 64;
  const int fr = l & 15, fq = l >> 4;
  f32x4 acc[4][4] = {};

  for (int kt = 0; kt < 1024; kt += 32) {
    __syncthreads();
#pragma unroll
    for (int i = 0; i < 2; i++) {
      int row = w * 32 + i * 16 + (l >> 2);
      int co = kt + (l & 3) * 8;
      size_t aoff = (size_t)(m0 + row) * 1024 + co;
      size_t boff = (size_t)(n0 + row) * 1024 + co;
      gload_lds16(Xhi  + aoff, Ah + w * 1024 + i * 512);
      gload_lds16(Xlo  + aoff, Al + w * 1024 + i * 512);
      gload_lds16(WhiT + boff, Bh + w * 1024 + i * 512);
      gload_lds16(WloT + boff, Bl + w * 1024 + i * 512);
    }
    __syncthreads();
    h8 ah[4], al[4], bh[4], bl[4];
#pragma unroll
    for (int m = 0; m < 4; m++) {
      ah[m] = *(h8*)&Ah[(wr + m * 16 + fr) * 32 + fq * 8];
      al[m] = *(h8*)&Al[(wr + m * 16 + fr) * 32 + fq * 8];
    }
#pragma unroll
    for (int n = 0; n < 4; n++) {
      bh[n] = *(h8*)&Bh[(wc + n * 16 + fr) * 32 + fq * 8];
      bl[n] = *(h8*)&Bl[(wc + n * 16 + fr) * 32 + fq * 8];
    }
#pragma unroll
    for (int m = 0; m < 4; m++)
#pragma unroll
      for (int n = 0; n < 4; n++) {
        acc[m][n] = MFMA(ah[m], bh[n], acc[m][n]);
        acc[m][n] = MFMA(al[m], bh[n], acc[m][n]);
        acc[m][n] = MFMA(ah[m], bl[n], acc[m][n]);
      }
  }

#pragma unroll
  for (int m = 0; m < 4; m++)
#pragma unroll
    for (int n = 0; n < 4; n++)
#pragma unroll
      for (int j = 0; j < 4; j++) {
        int row = m0 + wr + m * 16 + fq * 4 + j;
        int col = n0 + wc + n * 16 + fr;
        float val = acc[m][n][j] * (1.f / 262144.f) + bias[col];
        int t = col >> 10, h = (col >> 6) & 15, d = col & 63;
        int b = row >> 10, s = row & 1023;
        size_t idx = ((size_t)(b * 16 + h) * 1024 + s) * 64 + d;
        if (t == 0) { f16 hh = (f16)(val * 64.f); Qhi[idx] = hh; Qlo[idx] = (f16)(val * 64.f - (float)hh); }
        else if (t == 1) { f16 hh = (f16)(val * 64.f); Khi[idx] = hh; Klo[idx] = (f16)(val * 64.f - (float)hh); }
        else Vf[idx] = (f16)val;
      }
}

// ---------------------------------------------------------------------------
// FUSED QK^T + softmax/threshold/argmax-filter, v2 (occupancy-fixed).
// 16 q-rows/block; P logits fp32 [16][1024] in 64KB LDS -> 2 WG/CU.
// K hi/lo fragments loaded DIRECTLY global->VGPR (L2-resident per bh; no K
// staging, no __syncthreads in the K loop -- waves write disjoint P columns).
// One barrier, then per-row wave-parallel softmax/filter -> direct att store.
// MFMA product order identical to round-3/4 -> bitwise-same logits.
// ---------------------------------------------------------------------------
__global__ __launch_bounds__(256)
void qksm(const f16* __restrict__ Qhi, const f16* __restrict__ Qlo,
          const f16* __restrict__ Khi, const f16* __restrict__ Klo,
          float* __restrict__ att) {
  __shared__ float P[16][1024];                      // 64 KB -> 2 WG/CU
  const int bh = blockIdx.y, m0 = blockIdx.x * 16;
  const size_t off = (size_t)bh * 65536;
  const int tid = threadIdx.x, w = tid >> 6, l = tid & 63;
  const int fr = l & 15, fq = l >> 4;
  const int nw = w * 16;                             // this wave's k-col slice

  // Q fragments (rows m0..m0+15), register-resident
  h8 qh[2], ql[2];
#pragma unroll
  for (int kk = 0; kk < 2; kk++) {
    size_t o = off + (size_t)(m0 + fr) * 64 + kk * 32 + fq * 8;
    qh[kk] = *(const h8*)(Qhi + o);
    ql[kk] = *(const h8*)(Qlo + o);
  }

  for (int c = 0; c < 16; c++) {
    f32x4 acc = {};
    const int krow = c * 64 + nw + fr;               // k-col handled by this lane
#pragma unroll
    for (int kk = 0; kk < 2; kk++) {
      size_t o = off + (size_t)krow * 64 + kk * 32 + fq * 8;
      h8 b_h = *(const h8*)(Khi + o);
      h8 b_l = *(const h8*)(Klo + o);
      acc = MFMA(qh[kk], b_h, acc);
      acc = MFMA(ql[kk], b_h, acc);
      acc = MFMA(qh[kk], b_l, acc);
    }
#pragma unroll
    for (int j = 0; j < 4; j++)
      P[fq * 4 + j][c * 64 + nw + fr] = acc[j] * (1.f / 32768.f);
  }
  __syncthreads();

  // per-row wave-parallel softmax -> filter -> direct global store (4 rows/wave)
  for (int rr = 0; rr < 4; rr++) {
    const int r = w * 4 + rr;
    float z[16];
#pragma unroll
    for (int i = 0; i < 16; i++) z[i] = P[r][l + 64 * i];
    float m = z[0]; int am = l;
#pragma unroll
    for (int i = 1; i < 16; i++) { int idx = l + 64 * i; if (z[i] > m) { m = z[i]; am = idx; } }
#pragma unroll
    for (int o = 32; o >= 1; o >>= 1) {
      float om = __shfl_xor(m, o, 64);
      int oa = __shfl_xor(am, o, 64);
      if (om > m || (om == m && oa < am)) { m = om; am = oa; }
    }
    float e[16]; float s = 0.f;
#pragma unroll
    for (int i = 0; i < 16; i++) { e[i] = expf(z[i] - m); s += e[i]; }
#pragma unroll
    for (int o = 32; o >= 1; o >>= 1) s += __shfl_xor(s, o, 64);
    bool sel[16]; float fl = 0.f; int anyl = 0;
#pragma unroll
    for (int i = 0; i < 16; i++) {
      sel[i] = (e[i] / s > 0.1f);
      if (sel[i]) { fl += e[i]; anyl = 1; }
    }
#pragma unroll
    for (int o = 32; o >= 1; o >>= 1) fl += __shfl_xor(fl, o, 64);
    int any = __any(anyl);
    float* arow = att + ((size_t)bh << 20) + (size_t)(m0 + r) * 1024;
#pragma unroll
    for (int i = 0; i < 16; i++) {
      float v;
      if (any) v = sel[i] ? e[i] / fl : 0.f;
      else     v = ((l + 64 * i) == am) ? 1.f : 0.f;
      arow[l + 64 * i] = v;
    }
  }
}

// ---------------------------------------------------------------------------
// PV: batched f16 MFMA.  A = filtered_attn fp32 (reg-staged->f16; one-hots
// are exact), B = Vt f16 [bh][64 d][1024 s].  Tile 128x64. Out: ao16 f16.
// ---------------------------------------------------------------------------
__global__ __launch_bounds__(256)
void pv_gemm(const float* __restrict__ att, const f16* __restrict__ Vt,
             f16* __restrict__ ao) {
  __shared__ __align__(16) f16 A[128 * 32], B[64 * 32];
  const int bh = blockIdx.y, m0 = blockIdx.x * 128;
  const float* fa = att + (size_t)bh * 1048576;
  const f16* Vb = Vt + (size_t)bh * 65536;
  const int tid = threadIdx.x, w = tid >> 6, l = tid & 63;
  const int wr = (w & 1) * 64, wc = (w >> 1) * 32;
  const int fr = l & 15, fq = l >> 4;
  f32x4 acc[4][2] = {};

  for (int kt = 0; kt < 1024; kt += 32) {
    __syncthreads();
    {
      int row = w * 16 + (l >> 2);
      gload_lds16(Vb + (size_t)row * 1024 + kt + (l & 3) * 8, B + w * 512);
    }
#pragma unroll
    for (int r4 = 0; r4 < 4; r4++) {
      int f = r4 * 256 + tid;
      int row = f >> 3, c4 = (f & 7) * 4;
      float4 pv4 = *(const float4*)&fa[(size_t)(m0 + row) * 1024 + kt + c4];
      h4 hh;
      hh[0] = (f16)pv4.x; hh[1] = (f16)pv4.y; hh[2] = (f16)pv4.z; hh[3] = (f16)pv4.w;
      *(h4*)&A[row * 32 + c4] = hh;
    }
    __syncthreads();
    h8 a[4], b[2];
#pragma unroll
    for (int m = 0; m < 4; m++) a[m] = *(h8*)&A[(wr + m * 16 + fr) * 32 + fq * 8];
#pragma unroll
    for (int n = 0; n < 2; n++) b[n] = *(h8*)&B[(wc + n * 16 + fr) * 32 + fq * 8];
#pragma unroll
    for (int m = 0; m < 4; m++)
#pragma unroll
      for (int n = 0; n < 2; n++) acc[m][n] = MFMA(a[m], b[n], acc[m][n]);
  }

  const int b = bh >> 4, h = bh & 15;
#pragma unroll
  for (int m = 0; m < 4; m++)
#pragma unroll
    for (int n = 0; n < 2; n++)
#pragma unroll
      for (int j = 0; j < 4; j++) {
        int s = m0 + wr + m * 16 + fq * 4 + j;
        int d = wc + n * 16 + fr;
        ao[((size_t)(b * 1024 + s)) * 1024 + h * 64 + d] = (f16)acc[m][n][j];
      }
}

// ---------------------------------------------------------------------------
// proj: plain f16 MFMA.  A = ao16 [4096][1024], B = WpT [1024 n][1024 k].
// out fp32 = acc + bias.
// ---------------------------------------------------------------------------
__global__ __launch_bounds__(256)
void proj_gemm(const f16* __restrict__ ao, const f16* __restrict__ WpT,
               const float* __restrict__ bias, float* __restrict__ out) {
  __shared__ __align__(16) f16 A[128 * 32], B[128 * 32];
  const int tid = threadIdx.x, w = tid >> 6, l = tid & 63;
  const int n0 = blockIdx.x * 128, m0 = blockIdx.y * 128;
  const int wr = (w & 1) * 64, wc = (w >> 1) * 64;
  const int fr = l & 15, fq = l >> 4;
  f32x4 acc[4][4] = {};

  for (int kt = 0; kt < 1024; kt += 32) {
    __syncthreads();
#pragma unroll
    for (int i = 0; i < 2; i++) {
      int row = w * 32 + i * 16 + (l >> 2);
      gload_lds16(ao  + (size_t)(m0 + row) * 1024 + kt + (l & 3) * 8, A + w * 1024 + i * 512);
      gload_lds16(WpT + (size_t)(n0 + row) * 1024 + kt + (l & 3) * 8, B + w * 1024 + i * 512);
    }
    __syncthreads();
    h8 a[4], b[4];
#pragma unroll
    for (int m = 0; m < 4; m++) a[m] = *(h8*)&A[(wr + m * 16 + fr) * 32 + fq * 8];
#pragma unroll
    for (int n = 0; n < 4; n++) b[n] = *(h8*)&B[(wc + n * 16 + fr) * 32 + fq * 8];
#pragma unroll
    for (int m = 0; m < 4; m++)
#pragma unroll
      for (int n = 0; n < 4; n++) acc[m][n] = MFMA(a[m], b[n], acc[m][n]);
  }

#pragma unroll
  for (int m = 0; m < 4; m++)
#pragma unroll
    for (int n = 0; n < 4; n++)
#pragma unroll
      for (int j = 0; j < 4; j++) {
        int row = m0 + wr + m * 16 + fq * 4 + j;
        int col = n0 + wc + n * 16 + fr;
        out[(size_t)row * 1024 + col] = acc[m][n][j] + bias[col];
      }
}

// ---------------------------------------------------------------------------
extern "C" void kernel_launch(void* const* d_in, const int* in_sizes, int n_in,
                              void* d_out, int out_size, void* d_ws, size_t ws_size,
                              hipStream_t stream) {
  const float* x      = (const float*)d_in[0];
  const float* w_qkv  = (const float*)d_in[1];
  const float* b_qkv  = (const float*)d_in[2];
  const float* w_proj = (const float*)d_in[3];
  const float* b_proj = (const float*)d_in[4];

  float* out0 = (float*)d_out;
  float* att  = out0 + OUT0_SZ;            // [B,H,S,S] filtered_attn (output)

  // x hi/lo split parked in the att region (dead until qksm writes it)
  f16* Xhi = (f16*)att;                    // 8 MB
  f16* Xlo = Xhi + 4194304;                // 8 MB  (16 MB << 268 MB region)

  f16* ws16 = (f16*)d_ws;                  // 65.0 MB peak (proven available)
  f16* WhiT = ws16;                        // [3072][1024]
  f16* WloT = ws16 +  3145728;
  f16* WpT  = ws16 +  6291456;             // [1024][1024]
  f16* Qhi  = ws16 +  7340032;             // [64][1024][64] each
  f16* Qlo  = ws16 + 11534336;
  f16* Khi  = ws16 + 15728640;
  f16* Klo  = ws16 + 19922944;
  f16* Vf   = ws16 + 24117248;             // [64][1024][64]
  f16* Vt   = ws16 + 28311552;             // [64][64][1024]
  f16* ao16 = ws16;                        // aliases WhiT/WloT (dead after qkv)

  transpose_split<1><<<dim3(96, 32), 256, 0, stream>>>(w_qkv, WhiT, WloT, 1024, 3072, 4096.f);
  transpose_split<0><<<dim3(32, 32), 256, 0, stream>>>(w_proj, WpT, nullptr, 1024, 1024, 1.f);
  splitx<<<4096, 256, 0, stream>>>(x, Xhi, Xlo);
  qkv_gemm<<<dim3(24, 32), 256, 0, stream>>>(Xhi, Xlo, WhiT, WloT, b_qkv, Qhi, Qlo, Khi, Klo, Vf);
  transpose_v<<<dim3(32, 2, 64), 256, 0, stream>>>(Vf, Vt);
  qksm<<<dim3(64, 64), 256, 0, stream>>>(Qhi, Qlo, Khi, Klo, att);
  pv_gemm<<<dim3(8, 64), 256, 0, stream>>>(att, Vt, ao16);
  proj_gemm<<<dim3(8, 32), 256, 0, stream>>>(ao16, WpT, b_proj, out0);
}

// Round 6
// 613.304 us; speedup vs baseline: 1.1854x; 1.0617x over previous
//
#include <hip/hip_runtime.h>
#include <math.h>

// B=4, S=1024, E=1024, H=16, Dh=64
#define SS 1024
#define OUT0_SZ (4*1024*1024)

typedef _Float16 f16;
typedef _Float16 h8 __attribute__((ext_vector_type(8)));
typedef _Float16 h4 __attribute__((ext_vector_type(4)));
typedef float f32x4 __attribute__((ext_vector_type(4)));

#define MFMA(a,b,c) __builtin_amdgcn_mfma_f32_16x16x32_f16(a, b, c, 0, 0, 0)

__device__ __forceinline__ void gload_lds16(const void* g, void* l) {
  __builtin_amdgcn_global_load_lds((const __attribute__((address_space(1))) void*)g,
                                   (__attribute__((address_space(3))) void*)l, 16, 0, 0);
}

// ---------------------------------------------------------------------------
// transpose + (optional split) fp32 [K][N] -> f16 [N][K], scaled by `scale`
// ---------------------------------------------------------------------------
template<int SPLIT>
__global__ __launch_bounds__(256)
void transpose_split(const float* __restrict__ in, f16* __restrict__ outHi,
                     f16* __restrict__ outLo, int K, int N, float scale) {
  __shared__ float t[32][33];
  const int n0 = blockIdx.x * 32, k0 = blockIdx.y * 32;
  const int tx = threadIdx.x & 31, ty = threadIdx.x >> 5;   // ty 0..7
#pragma unroll
  for (int j = 0; j < 4; j++)
    t[ty + j * 8][tx] = in[(size_t)(k0 + ty + j * 8) * N + n0 + tx] * scale;
  __syncthreads();
#pragma unroll
  for (int j = 0; j < 4; j++) {
    float v = t[tx][ty + j * 8];
    f16 h = (f16)v;
    size_t idx = (size_t)(n0 + ty + j * 8) * K + k0 + tx;
    outHi[idx] = h;
    if (SPLIT) outLo[idx] = (f16)(v - (float)h);
  }
}

// ---------------------------------------------------------------------------
// elementwise split: x fp32 -> (x*64) hi/lo f16
// ---------------------------------------------------------------------------
__global__ __launch_bounds__(256)
void splitx(const float* __restrict__ x, f16* __restrict__ hi, f16* __restrict__ lo) {
  const size_t i4 = (size_t)blockIdx.x * 256 + threadIdx.x;   // float4 index
  float4 v = ((const float4*)x)[i4];
  float vv[4] = {v.x, v.y, v.z, v.w};
  h4 hh, ll;
#pragma unroll
  for (int j = 0; j < 4; j++) {
    float sv = vv[j] * 64.f;
    f16 h = (f16)sv;
    hh[j] = h; ll[j] = (f16)(sv - (float)h);
  }
  ((h4*)hi)[i4] = hh;
  ((h4*)lo)[i4] = ll;
}

// ---------------------------------------------------------------------------
// V transpose: f16 [bh][1024 s][64 d] -> [bh][64 d][1024 s]
// ---------------------------------------------------------------------------
__global__ __launch_bounds__(256)
void transpose_v(const f16* __restrict__ in, f16* __restrict__ out) {
  __shared__ f16 t[32][33];
  const int bh = blockIdx.z, s0 = blockIdx.x * 32, d0 = blockIdx.y * 32;
  in  += (size_t)bh * 65536;
  out += (size_t)bh * 65536;
  const int tx = threadIdx.x & 31, ty = threadIdx.x >> 5;
#pragma unroll
  for (int j = 0; j < 4; j++)
    t[ty + j * 8][tx] = in[(size_t)(s0 + ty + j * 8) * 64 + d0 + tx];
  __syncthreads();
#pragma unroll
  for (int j = 0; j < 4; j++)
    out[(size_t)(d0 + ty + j * 8) * 1024 + s0 + tx] = t[tx][ty + j * 8];
}

// ---------------------------------------------------------------------------
// QKV GEMM: split-f16 MFMA.  Xhi/Xlo f16 [4096][1024] (A, global_load_lds);
// WhiT/WloT f16 [3072 n][1024 k] (B, global_load_lds, pre-scaled 2^12).
// acc * 2^-18 + bias -> scatter: q,k re-split (scale 2^6); v -> f16 Vf.
// ---------------------------------------------------------------------------
__global__ __launch_bounds__(256)
void qkv_gemm(const f16* __restrict__ Xhi, const f16* __restrict__ Xlo,
              const f16* __restrict__ WhiT, const f16* __restrict__ WloT,
              const float* __restrict__ bias,
              f16* __restrict__ Qhi, f16* __restrict__ Qlo,
              f16* __restrict__ Khi, f16* __restrict__ Klo, f16* __restrict__ Vf) {
  __shared__ __align__(16) f16 Ah[128 * 32], Al[128 * 32], Bh[128 * 32], Bl[128 * 32];
  const int tid = threadIdx.x, w = tid >> 6, l = tid & 63;
  const int n0 = blockIdx.x * 128, m0 = blockIdx.y * 128;
  const int wr = (w & 1) * 64, wc = (w >> 1) * 64;
  const int fr = l & 15, fq = l >> 4;
  f32x4 acc[4][4] = {};

  for (int kt = 0; kt < 1024; kt += 32) {
    __syncthreads();
#pragma unroll
    for (int i = 0; i < 2; i++) {
      int row = w * 32 + i * 16 + (l >> 2);
      int co = kt + (l & 3) * 8;
      size_t aoff = (size_t)(m0 + row) * 1024 + co;
      size_t boff = (size_t)(n0 + row) * 1024 + co;
      gload_lds16(Xhi  + aoff, Ah + w * 1024 + i * 512);
      gload_lds16(Xlo  + aoff, Al + w * 1024 + i * 512);
      gload_lds16(WhiT + boff, Bh + w * 1024 + i * 512);
      gload_lds16(WloT + boff, Bl + w * 1024 + i * 512);
    }
    __syncthreads();
    h8 ah[4], al[4], bh[4], bl[4];
#pragma unroll
    for (int m = 0; m < 4; m++) {
      ah[m] = *(h8*)&Ah[(wr + m * 16 + fr) * 32 + fq * 8];
      al[m] = *(h8*)&Al[(wr + m * 16 + fr) * 32 + fq * 8];
    }
#pragma unroll
    for (int n = 0; n < 4; n++) {
      bh[n] = *(h8*)&Bh[(wc + n * 16 + fr) * 32 + fq * 8];
      bl[n] = *(h8*)&Bl[(wc + n * 16 + fr) * 32 + fq * 8];
    }
#pragma unroll
    for (int m = 0; m < 4; m++)
#pragma unroll
      for (int n = 0; n < 4; n++) {
        acc[m][n] = MFMA(ah[m], bh[n], acc[m][n]);
        acc[m][n] = MFMA(al[m], bh[n], acc[m][n]);
        acc[m][n] = MFMA(ah[m], bl[n], acc[m][n]);
      }
  }

#pragma unroll
  for (int m = 0; m < 4; m++)
#pragma unroll
    for (int n = 0; n < 4; n++)
#pragma unroll
      for (int j = 0; j < 4; j++) {
        int row = m0 + wr + m * 16 + fq * 4 + j;
        int col = n0 + wc + n * 16 + fr;
        float val = acc[m][n][j] * (1.f / 262144.f) + bias[col];
        int t = col >> 10, h = (col >> 6) & 15, d = col & 63;
        int b = row >> 10, s = row & 1023;
        size_t idx = ((size_t)(b * 16 + h) * 1024 + s) * 64 + d;
        if (t == 0) { f16 hh = (f16)(val * 64.f); Qhi[idx] = hh; Qlo[idx] = (f16)(val * 64.f - (float)hh); }
        else if (t == 1) { f16 hh = (f16)(val * 64.f); Khi[idx] = hh; Klo[idx] = (f16)(val * 64.f - (float)hh); }
        else Vf[idx] = (f16)val;
      }
}

// ---------------------------------------------------------------------------
// FUSED QK^T + softmax/threshold/argmax-filter, v3 (512 threads, padded P).
// 16 q-rows/block; P fp32 [16][1028] (64.25 KB) -> 2 WG x 8 waves = 16
// waves/CU.  K hi/lo fragments loaded directly global->VGPR (L2-resident);
// no barrier in the K loop (waves own disjoint P columns).  One barrier,
// then per-row wave-parallel softmax/filter -> direct att store.
// MFMA product order identical to rounds 3-5 -> bitwise-same logits.
// ---------------------------------------------------------------------------
__global__ __launch_bounds__(512)
void qksm(const f16* __restrict__ Qhi, const f16* __restrict__ Qlo,
          const f16* __restrict__ Khi, const f16* __restrict__ Klo,
          float* __restrict__ att) {
  __shared__ float P[16][1028];                      // pad: write conflicts 4->2-way (free)
  const int bh = blockIdx.y, m0 = blockIdx.x * 16;
  const size_t off = (size_t)bh * 65536;
  const int tid = threadIdx.x, w = tid >> 6, l = tid & 63;
  const int fr = l & 15, fq = l >> 4;
  const int nw = w * 16;                             // this wave's k-col slice base

  // Q fragments (rows m0..m0+15), register-resident
  h8 qh[2], ql[2];
#pragma unroll
  for (int kk = 0; kk < 2; kk++) {
    size_t o = off + (size_t)(m0 + fr) * 64 + kk * 32 + fq * 8;
    qh[kk] = *(const h8*)(Qhi + o);
    ql[kk] = *(const h8*)(Qlo + o);
  }

#pragma unroll
  for (int c = 0; c < 8; c++) {
    f32x4 acc = {};
    const int krow = c * 128 + nw + fr;              // k-col handled by this lane
#pragma unroll
    for (int kk = 0; kk < 2; kk++) {
      size_t o = off + (size_t)krow * 64 + kk * 32 + fq * 8;
      h8 b_h = *(const h8*)(Khi + o);
      h8 b_l = *(const h8*)(Klo + o);
      acc = MFMA(qh[kk], b_h, acc);
      acc = MFMA(ql[kk], b_h, acc);
      acc = MFMA(qh[kk], b_l, acc);
    }
#pragma unroll
    for (int j = 0; j < 4; j++)
      P[fq * 4 + j][c * 128 + nw + fr] = acc[j] * (1.f / 32768.f);
  }
  __syncthreads();

  // per-row wave-parallel softmax -> filter -> direct global store (2 rows/wave)
#pragma unroll
  for (int rr = 0; rr < 2; rr++) {
    const int r = w * 2 + rr;
    float z[16];
#pragma unroll
    for (int i = 0; i < 16; i++) z[i] = P[r][l + 64 * i];
    float m = z[0]; int am = l;
#pragma unroll
    for (int i = 1; i < 16; i++) { int idx = l + 64 * i; if (z[i] > m) { m = z[i]; am = idx; } }
#pragma unroll
    for (int o = 32; o >= 1; o >>= 1) {
      float om = __shfl_xor(m, o, 64);
      int oa = __shfl_xor(am, o, 64);
      if (om > m || (om == m && oa < am)) { m = om; am = oa; }
    }
    float e[16]; float s = 0.f;
#pragma unroll
    for (int i = 0; i < 16; i++) { e[i] = expf(z[i] - m); s += e[i]; }
#pragma unroll
    for (int o = 32; o >= 1; o >>= 1) s += __shfl_xor(s, o, 64);
    const float thr = 0.1f * s;                      // sel: e/s > 0.1  <=>  e > 0.1*s
    bool sel[16]; float fl = 0.f; int anyl = 0;
#pragma unroll
    for (int i = 0; i < 16; i++) {
      sel[i] = (e[i] > thr);
      if (sel[i]) { fl += e[i]; anyl = 1; }
    }
#pragma unroll
    for (int o = 32; o >= 1; o >>= 1) fl += __shfl_xor(fl, o, 64);
    int any = __any(anyl);
    const float inv_fl = 1.0f / fl;                  // 1 divide instead of 16
    float* arow = att + ((size_t)bh << 20) + (size_t)(m0 + r) * 1024;
#pragma unroll
    for (int i = 0; i < 16; i++) {
      float v;
      if (any) v = sel[i] ? e[i] * inv_fl : 0.f;
      else     v = ((l + 64 * i) == am) ? 1.f : 0.f;
      arow[l + 64 * i] = v;
    }
  }
}

// ---------------------------------------------------------------------------
// PV: batched f16 MFMA.  A = filtered_attn fp32 (reg-staged->f16; one-hots
// are exact), B = Vt f16 [bh][64 d][1024 s].  Tile 128x64. Out: ao16 f16.
// ---------------------------------------------------------------------------
__global__ __launch_bounds__(256)
void pv_gemm(const float* __restrict__ att, const f16* __restrict__ Vt,
             f16* __restrict__ ao) {
  __shared__ __align__(16) f16 A[128 * 32], B[64 * 32];
  const int bh = blockIdx.y, m0 = blockIdx.x * 128;
  const float* fa = att + (size_t)bh * 1048576;
  const f16* Vb = Vt + (size_t)bh * 65536;
  const int tid = threadIdx.x, w = tid >> 6, l = tid & 63;
  const int wr = (w & 1) * 64, wc = (w >> 1) * 32;
  const int fr = l & 15, fq = l >> 4;
  f32x4 acc[4][2] = {};

  for (int kt = 0; kt < 1024; kt += 32) {
    __syncthreads();
    {
      int row = w * 16 + (l >> 2);
      gload_lds16(Vb + (size_t)row * 1024 + kt + (l & 3) * 8, B + w * 512);
    }
#pragma unroll
    for (int r4 = 0; r4 < 4; r4++) {
      int f = r4 * 256 + tid;
      int row = f >> 3, c4 = (f & 7) * 4;
      float4 pv4 = *(const float4*)&fa[(size_t)(m0 + row) * 1024 + kt + c4];
      h4 hh;
      hh[0] = (f16)pv4.x; hh[1] = (f16)pv4.y; hh[2] = (f16)pv4.z; hh[3] = (f16)pv4.w;
      *(h4*)&A[row * 32 + c4] = hh;
    }
    __syncthreads();
    h8 a[4], b[2];
#pragma unroll
    for (int m = 0; m < 4; m++) a[m] = *(h8*)&A[(wr + m * 16 + fr) * 32 + fq * 8];
#pragma unroll
    for (int n = 0; n < 2; n++) b[n] = *(h8*)&B[(wc + n * 16 + fr) * 32 + fq * 8];
#pragma unroll
    for (int m = 0; m < 4; m++)
#pragma unroll
      for (int n = 0; n < 2; n++) acc[m][n] = MFMA(a[m], b[n], acc[m][n]);
  }

  const int b = bh >> 4, h = bh & 15;
#pragma unroll
  for (int m = 0; m < 4; m++)
#pragma unroll
    for (int n = 0; n < 2; n++)
#pragma unroll
      for (int j = 0; j < 4; j++) {
        int s = m0 + wr + m * 16 + fq * 4 + j;
        int d = wc + n * 16 + fr;
        ao[((size_t)(b * 1024 + s)) * 1024 + h * 64 + d] = (f16)acc[m][n][j];
      }
}

// ---------------------------------------------------------------------------
// proj: plain f16 MFMA.  A = ao16 [4096][1024], B = WpT [1024 n][1024 k].
// out fp32 = acc + bias.
// ---------------------------------------------------------------------------
__global__ __launch_bounds__(256)
void proj_gemm(const f16* __restrict__ ao, const f16* __restrict__ WpT,
               const float* __restrict__ bias, float* __restrict__ out) {
  __shared__ __align__(16) f16 A[128 * 32], B[128 * 32];
  const int tid = threadIdx.x, w = tid >> 6, l = tid & 63;
  const int n0 = blockIdx.x * 128, m0 = blockIdx.y * 128;
  const int wr = (w & 1) * 64, wc = (w >> 1) * 64;
  const int fr = l & 15, fq = l >> 4;
  f32x4 acc[4][4] = {};

  for (int kt = 0; kt < 1024; kt += 32) {
    __syncthreads();
#pragma unroll
    for (int i = 0; i < 2; i++) {
      int row = w * 32 + i * 16 + (l >> 2);
      gload_lds16(ao  + (size_t)(m0 + row) * 1024 + kt + (l & 3) * 8, A + w * 1024 + i * 512);
      gload_lds16(WpT + (size_t)(n0 + row) * 1024 + kt + (l & 3) * 8, B + w * 1024 + i * 512);
    }
    __syncthreads();
    h8 a[4], b[4];
#pragma unroll
    for (int m = 0; m < 4; m++) a[m] = *(h8*)&A[(wr + m * 16 + fr) * 32 + fq * 8];
#pragma unroll
    for (int n = 0; n < 4; n++) b[n] = *(h8*)&B[(wc + n * 16 + fr) * 32 + fq * 8];
#pragma unroll
    for (int m = 0; m < 4; m++)
#pragma unroll
      for (int n = 0; n < 4; n++) acc[m][n] = MFMA(a[m], b[n], acc[m][n]);
  }

#pragma unroll
  for (int m = 0; m < 4; m++)
#pragma unroll
    for (int n = 0; n < 4; n++)
#pragma unroll
      for (int j = 0; j < 4; j++) {
        int row = m0 + wr + m * 16 + fq * 4 + j;
        int col = n0 + wc + n * 16 + fr;
        out[(size_t)row * 1024 + col] = acc[m][n][j] + bias[col];
      }
}

// ---------------------------------------------------------------------------
extern "C" void kernel_launch(void* const* d_in, const int* in_sizes, int n_in,
                              void* d_out, int out_size, void* d_ws, size_t ws_size,
                              hipStream_t stream) {
  const float* x      = (const float*)d_in[0];
  const float* w_qkv  = (const float*)d_in[1];
  const float* b_qkv  = (const float*)d_in[2];
  const float* w_proj = (const float*)d_in[3];
  const float* b_proj = (const float*)d_in[4];

  float* out0 = (float*)d_out;
  float* att  = out0 + OUT0_SZ;            // [B,H,S,S] filtered_attn (output)

  // x hi/lo split parked in the att region (dead until qksm writes it)
  f16* Xhi = (f16*)att;                    // 8 MB
  f16* Xlo = Xhi + 4194304;                // 8 MB  (16 MB << 268 MB region)

  f16* ws16 = (f16*)d_ws;                  // 65.0 MB peak (proven available)
  f16* WhiT = ws16;                        // [3072][1024]
  f16* WloT = ws16 +  3145728;
  f16* WpT  = ws16 +  6291456;             // [1024][1024]
  f16* Qhi  = ws16 +  7340032;             // [64][1024][64] each
  f16* Qlo  = ws16 + 11534336;
  f16* Khi  = ws16 + 15728640;
  f16* Klo  = ws16 + 19922944;
  f16* Vf   = ws16 + 24117248;             // [64][1024][64]
  f16* Vt   = ws16 + 28311552;             // [64][64][1024]
  f16* ao16 = ws16;                        // aliases WhiT/WloT (dead after qkv)

  transpose_split<1><<<dim3(96, 32), 256, 0, stream>>>(w_qkv, WhiT, WloT, 1024, 3072, 4096.f);
  transpose_split<0><<<dim3(32, 32), 256, 0, stream>>>(w_proj, WpT, nullptr, 1024, 1024, 1.f);
  splitx<<<4096, 256, 0, stream>>>(x, Xhi, Xlo);
  qkv_gemm<<<dim3(24, 32), 256, 0, stream>>>(Xhi, Xlo, WhiT, WloT, b_qkv, Qhi, Qlo, Khi, Klo, Vf);
  transpose_v<<<dim3(32, 2, 64), 256, 0, stream>>>(Vf, Vt);
  qksm<<<dim3(64, 64), 512, 0, stream>>>(Qhi, Qlo, Khi, Klo, att);
  pv_gemm<<<dim3(8, 64), 256, 0, stream>>>(att, Vt, ao16);
  proj_gemm<<<dim3(8, 32), 256, 0, stream>>>(ao16, WpT, b_proj, out0);
}